// Round 2
// baseline (1538.761 us; speedup 1.0000x reference)
//
#include <hip/hip_runtime.h>
#include <hip/hip_bf16.h>

#define NN 4608
#define BG 48
#define NPG 96
#define DD 512
#define XDIM 16
#define EREAL 147456
#define ETOT 152064   // EREAL + NN self loops
#define NLAYER 6
#define ECLOUD 223488 // BG * 4656

// ---------- x projection: h = x @ Wp + bp ; xg = h ----------
__global__ void k_xproj(const float* __restrict__ x, const float* __restrict__ w,
                        const float* __restrict__ b, float* __restrict__ h,
                        float* __restrict__ xg) {
  int i = blockIdx.x * blockDim.x + threadIdx.x;
  if (i >= NN * DD) return;
  int n = i >> 9, d = i & 511;
  float acc = b[d];
#pragma unroll
  for (int k = 0; k < XDIM; k++) acc += x[n * XDIM + k] * w[k * DD + d];
  h[i] = acc;
  xg[i] = acc;
}

// ---------- edge sort (counting sort by dst) ----------
__global__ void k_init_counts(int* counts) {
  int i = blockIdx.x * blockDim.x + threadIdx.x;
  if (i < NN) counts[i] = 1;  // self loop
}
__global__ void k_hist(const int* __restrict__ ei, int* counts) {
  int e = blockIdx.x * blockDim.x + threadIdx.x;
  if (e < EREAL) atomicAdd(&counts[ei[EREAL + e]], 1);
}
__global__ void k_scan(const int* __restrict__ counts, int* offsets, int* cursor) {
  __shared__ int part[256];
  __shared__ int pre[256];
  int t = threadIdx.x;
  int base = t * 18;  // 4608/256
  int s = 0;
#pragma unroll
  for (int i = 0; i < 18; i++) s += counts[base + i];
  part[t] = s;
  __syncthreads();
  if (t == 0) {
    int r = 0;
    for (int i = 0; i < 256; i++) { pre[i] = r; r += part[i]; }
  }
  __syncthreads();
  int run = pre[t];
#pragma unroll
  for (int i = 0; i < 18; i++) {
    offsets[base + i] = run;
    cursor[base + i] = run;
    run += counts[base + i];
  }
  if (t == 0) offsets[NN] = ETOT;
}
__global__ void k_scatter(const int* __restrict__ ei, int* cursor, int* ssrc) {
  int e = blockIdx.x * blockDim.x + threadIdx.x;
  if (e < EREAL) {
    int s = ei[e], d = ei[EREAL + e];
    int pos = atomicAdd(&cursor[d], 1);
    ssrc[pos] = s;
  } else if (e < ETOT) {
    int n = e - EREAL;
    int pos = atomicAdd(&cursor[n], 1);
    ssrc[pos] = n;
  }
}

// ---------- generic matmul: C[M,512] = A[M,512] @ Bw[512,512] + bias ----------
// BM=128, BN=64, BK=16, 256 thr, 8x4 per thread. All fp32.
__global__ __launch_bounds__(256) void k_matmul(const float* __restrict__ A,
                                                const float* __restrict__ Bw,
                                                const float* __restrict__ bias,
                                                float* __restrict__ C) {
  __shared__ float As[16][132];
  __shared__ float Bs[16][68];
  int tid = threadIdx.x;
  int m0 = blockIdx.x * 128;
  int n0 = blockIdx.y * 64;
  int tx = tid & 15, ty = tid >> 4;
  float acc[8][4];
#pragma unroll
  for (int i = 0; i < 8; i++)
#pragma unroll
    for (int j = 0; j < 4; j++) acc[i][j] = 0.f;

  for (int k0 = 0; k0 < 512; k0 += 16) {
#pragma unroll
    for (int it = 0; it < 8; it++) {
      int idx = tid + it * 256;
      int r = idx >> 4, c = idx & 15;
      As[c][r] = A[(size_t)(m0 + r) * 512 + k0 + c];
    }
#pragma unroll
    for (int it = 0; it < 4; it++) {
      int idx = tid + it * 256;
      int r = idx >> 6, c = idx & 63;
      Bs[r][c] = Bw[(size_t)(k0 + r) * 512 + n0 + c];
    }
    __syncthreads();
#pragma unroll
    for (int kk = 0; kk < 16; kk++) {
      float4 a0 = *(const float4*)&As[kk][ty * 8];
      float4 a1 = *(const float4*)&As[kk][ty * 8 + 4];
      float4 b0 = *(const float4*)&Bs[kk][tx * 4];
      float av[8] = {a0.x, a0.y, a0.z, a0.w, a1.x, a1.y, a1.z, a1.w};
      float bv[4] = {b0.x, b0.y, b0.z, b0.w};
#pragma unroll
      for (int i = 0; i < 8; i++)
#pragma unroll
        for (int j = 0; j < 4; j++) acc[i][j] += av[i] * bv[j];
    }
    __syncthreads();
  }
#pragma unroll
  for (int i = 0; i < 8; i++) {
    int m = m0 + ty * 8 + i;
#pragma unroll
    for (int j = 0; j < 4; j++) {
      int n = n0 + tx * 4 + j;
      float v = acc[i][j] + (bias ? bias[n] : 0.f);
      C[(size_t)m * 512 + n] = v;
    }
  }
}

// ---------- GAT edge + online softmax + aggregate: one wave per dst node ----------
__global__ __launch_bounds__(256) void k_gat_edge(const float* __restrict__ xl,
                                                  const float* __restrict__ xr,
                                                  const float* __restrict__ att,
                                                  const float* __restrict__ bias,
                                                  const int* __restrict__ offs,
                                                  const int* __restrict__ ssrc,
                                                  float* __restrict__ out) {
  int wave = (blockIdx.x * blockDim.x + threadIdx.x) >> 6;
  int lane = threadIdx.x & 63;
  if (wave >= NN) return;
  int n = wave;
  float xrv[8], attv[8], acc[8];
#pragma unroll
  for (int k = 0; k < 8; k++) {
    int d = k * 64 + lane;
    xrv[k] = xr[(size_t)n * 512 + d];
    attv[k] = att[d];
    acc[k] = 0.f;
  }
  float m = -3.4e38f, lsum = 0.f;
  int e0 = offs[n], e1 = offs[n + 1];
  for (int e = e0; e < e1; ++e) {
    int s = ssrc[e];
    float xlv[8];
    float esc = 0.f;
#pragma unroll
    for (int k = 0; k < 8; k++) {
      float v = xl[(size_t)s * 512 + k * 64 + lane];
      xlv[k] = v;
      float t = v + xrv[k];
      t = (t > 0.f) ? t : 0.2f * t;
      esc += attv[k] * t;
    }
#pragma unroll
    for (int off = 32; off >= 1; off >>= 1) esc += __shfl_xor(esc, off, 64);
    float nm = fmaxf(m, esc);
    float sc = __expf(m - nm);   // first iter: exp(-big) = 0
    float p = __expf(esc - nm);
    lsum = lsum * sc + p;
#pragma unroll
    for (int k = 0; k < 8; k++) acc[k] = acc[k] * sc + p * xlv[k];
    m = nm;
  }
  float inv = 1.f / lsum;
#pragma unroll
  for (int k = 0; k < 8; k++) {
    int d = k * 64 + lane;
    out[(size_t)n * 512 + d] = acc[k] * inv + bias[d];
  }
}

// ---------- graph-mode LayerNorm over ALL elements + relu ----------
__global__ void k_zero(float* p, int n) {
  int i = blockIdx.x * blockDim.x + threadIdx.x;
  if (i < n) p[i] = 0.f;
}
__global__ void k_ln_reduce(const float* __restrict__ x, float* stats) {
  float s = 0.f, ss = 0.f;
  for (int i = blockIdx.x * blockDim.x + threadIdx.x; i < NN * DD;
       i += gridDim.x * blockDim.x) {
    float v = x[i];
    s += v;
    ss += v * v;
  }
#pragma unroll
  for (int off = 32; off >= 1; off >>= 1) {
    s += __shfl_xor(s, off, 64);
    ss += __shfl_xor(ss, off, 64);
  }
  __shared__ float sw[2][4];
  int lane = threadIdx.x & 63, w = threadIdx.x >> 6;
  if (lane == 0) { sw[0][w] = s; sw[1][w] = ss; }
  __syncthreads();
  if (threadIdx.x == 0) {
    float a = 0.f, b = 0.f;
    for (int i = 0; i < 4; i++) { a += sw[0][i]; b += sw[1][i]; }
    atomicAdd(&stats[0], a);
    atomicAdd(&stats[1], b);
  }
}
__global__ void k_ln_norm_relu(float* __restrict__ x, const float* __restrict__ stats,
                               const float* __restrict__ g, const float* __restrict__ b) {
  int i = blockIdx.x * blockDim.x + threadIdx.x;
  if (i >= NN * DD) return;
  const float invM = 1.f / (float)(NN * DD);
  float mu = stats[0] * invM;
  float var = stats[1] * invM - mu * mu;
  float sd = sqrtf(fmaxf(var, 0.f));
  float inv = 1.f / (sd + 1e-5f);
  int d = i & 511;
  float v = (x[i] - mu) * inv * g[d] + b[d];
  x[i] = fmaxf(v, 0.f);
}

// ---------- CloudGraph: one wave per node (a side of triu edges) ----------
__global__ __launch_bounds__(256) void k_cloud(const float* __restrict__ g1,
                                               const float* __restrict__ xyz,
                                               const int* __restrict__ cei_b,
                                               const float* __restrict__ lin1b,
                                               const float* __restrict__ w3,
                                               float* __restrict__ p1,
                                               float* __restrict__ p2) {
  int wave = (blockIdx.x * blockDim.x + threadIdx.x) >> 6;
  int lane = threadIdx.x & 63;
  if (wave >= NN) return;
  int n = wave;
  int p = n % NPG;
  int g = n / NPG;
  int start = g * 4656 + p * NPG - (p * (p - 1)) / 2;
  int cnt = NPG - p;
  float gi[8], bb[8], w30[8], w31[8], w32[8], a1[8], a2[8];
#pragma unroll
  for (int k = 0; k < 8; k++) {
    int d = k * 64 + lane;
    gi[k] = g1[(size_t)n * 512 + d];
    bb[k] = lin1b[d];
    w30[k] = w3[d];
    w31[k] = w3[512 + d];
    w32[k] = w3[1024 + d];
    a1[k] = 0.f;
    a2[k] = 0.f;
  }
  float xi0 = xyz[n * 3], xi1 = xyz[n * 3 + 1], xi2 = xyz[n * 3 + 2];
  for (int e = 0; e < cnt; ++e) {
    int j = cei_b[start + e];
    float dx = xi0 - xyz[j * 3];
    float dy = xi1 - xyz[j * 3 + 1];
    float dz = xi2 - xyz[j * 3 + 2];
    float sq = dx * dx + dy * dy + dz * dz;
    float dist = (sq > 0.f) ? sqrtf(sq) : 0.f;
    float w = __expf(-dist);
#pragma unroll
    for (int k = 0; k < 8; k++) {
      float t = w * (gi[k] - g1[(size_t)j * 512 + k * 64 + lane]) + bb[k];
      a1[k] += fmaxf(t, 0.f);
      float t2 = dx * w30[k] + dy * w31[k] + dz * w32[k];
      a2[k] += fmaxf(t2, 0.f);
    }
  }
#pragma unroll
  for (int k = 0; k < 8; k++) {
    int d = k * 64 + lane;
    p1[(size_t)n * 512 + d] = a1[k];
    p2[(size_t)n * 512 + d] = a2[k];
  }
}

// ---------- row LayerNorm (cloud ln1), in place ----------
__global__ __launch_bounds__(256) void k_ln_row(float* __restrict__ x,
                                                const float* __restrict__ g,
                                                const float* __restrict__ b) {
  int wave = (blockIdx.x * blockDim.x + threadIdx.x) >> 6;
  int lane = threadIdx.x & 63;
  if (wave >= NN) return;
  int n = wave;
  float v[8];
  float s = 0.f;
#pragma unroll
  for (int k = 0; k < 8; k++) {
    v[k] = x[(size_t)n * 512 + k * 64 + lane];
    s += v[k];
  }
#pragma unroll
  for (int off = 32; off >= 1; off >>= 1) s += __shfl_xor(s, off, 64);
  float mu = s * (1.f / 512.f);
  float ss = 0.f;
#pragma unroll
  for (int k = 0; k < 8; k++) {
    float t = v[k] - mu;
    ss += t * t;
  }
#pragma unroll
  for (int off = 32; off >= 1; off >>= 1) ss += __shfl_xor(ss, off, 64);
  float var = ss * (1.f / 512.f);
  float inv = 1.f / sqrtf(var + 1e-5f);
#pragma unroll
  for (int k = 0; k < 8; k++) {
    int d = k * 64 + lane;
    x[(size_t)n * 512 + d] = (v[k] - mu) * inv * g[d] + b[d];
  }
}

// ---------- column (batchnorm) stats ----------
__global__ void k_col_reduce(const float* __restrict__ x, float* colsum, float* colsq) {
  int r0 = blockIdx.x * 128;
  int c0 = threadIdx.x;  // owns columns c0 and c0+256
  float s0 = 0.f, q0 = 0.f, s1 = 0.f, q1 = 0.f;
  for (int r = r0; r < r0 + 128; ++r) {
    float v = x[(size_t)r * 512 + c0];
    s0 += v;
    q0 += v * v;
    float w = x[(size_t)r * 512 + c0 + 256];
    s1 += w;
    q1 += w * w;
  }
  atomicAdd(&colsum[c0], s0);
  atomicAdd(&colsq[c0], q0);
  atomicAdd(&colsum[c0 + 256], s1);
  atomicAdd(&colsq[c0 + 256], q1);
}
__global__ void k_bn_apply(float* __restrict__ x, const float* __restrict__ colsum,
                           const float* __restrict__ colsq, const float* __restrict__ g,
                           const float* __restrict__ b) {
  int i = blockIdx.x * blockDim.x + threadIdx.x;
  if (i >= NN * DD) return;
  int d = i & 511;
  float mu = colsum[d] * (1.f / NN);
  float var = colsq[d] * (1.f / NN) - mu * mu;
  float inv = 1.f / sqrtf(fmaxf(var, 0.f) + 1e-5f);
  x[i] = (x[i] - mu) * inv * g[d] + b[d];
}
// s = 2h + xg + p1 + p2 (into p2)
__global__ void k_fuse(float* __restrict__ p2, const float* __restrict__ h,
                       const float* __restrict__ xg, const float* __restrict__ p1) {
  int i = blockIdx.x * blockDim.x + threadIdx.x;
  if (i >= NN * DD) return;
  p2[i] = 2.f * h[i] + xg[i] + p1[i] + p2[i];
}
__global__ void k_bn_out(const float* __restrict__ y, const float* __restrict__ colsum,
                         const float* __restrict__ colsq, const float* __restrict__ g,
                         const float* __restrict__ b, float* __restrict__ out) {
  int i = blockIdx.x * blockDim.x + threadIdx.x;
  if (i >= NN * DD) return;
  int d = i & 511;
  float mu = colsum[d] * (1.f / NN);
  float var = colsq[d] * (1.f / NN) - mu * mu;
  float inv = 1.f / sqrtf(fmaxf(var, 0.f) + 1e-5f);
  out[i] = (y[i] - mu) * inv * g[d] + b[d];
}

extern "C" void kernel_launch(void* const* d_in, const int* in_sizes, int n_in,
                              void* d_out, int out_size, void* d_ws, size_t ws_size,
                              hipStream_t stream) {
  const float* x = (const float*)d_in[0];
  const int* ei = (const int*)d_in[1];
  const float* xyz = (const float*)d_in[3];
  const int* cei = (const int*)d_in[4];
  const float* x_proj_w = (const float*)d_in[5];
  const float* x_proj_b = (const float*)d_in[6];
  const float* gat_wl = (const float*)d_in[7];
  const float* gat_bl = (const float*)d_in[8];
  const float* gat_wr = (const float*)d_in[9];
  const float* gat_br = (const float*)d_in[10];
  const float* gat_att = (const float*)d_in[11];
  const float* gat_bias = (const float*)d_in[12];
  const float* gat_ln_g = (const float*)d_in[13];
  const float* gat_ln_b = (const float*)d_in[14];
  const float* cg_xyz_w = (const float*)d_in[15];
  const float* cg_bn_g = (const float*)d_in[16];
  const float* cg_bn_b = (const float*)d_in[17];
  const float* cg_lin1_w = (const float*)d_in[18];
  const float* cg_lin1_b = (const float*)d_in[19];
  const float* cg_ln_g = (const float*)d_in[20];
  const float* cg_ln_b = (const float*)d_in[21];
  const float* lin_w = (const float*)d_in[22];
  const float* lin_b = (const float*)d_in[23];
  const float* bn_g = (const float*)d_in[24];
  const float* bn_b = (const float*)d_in[25];

  const size_t ND = (size_t)NN * DD;
  char* w = (char*)d_ws;
  float* h = (float*)w;            w += ND * 4;
  float* xg = (float*)w;           w += ND * 4;
  float* xl = (float*)w;           w += ND * 4;   // also final-matmul out y
  float* xr = (float*)w;           w += ND * 4;   // also g1
  float* p1 = (float*)w;           w += ND * 4;
  float* p2 = (float*)w;           w += ND * 4;   // also fused s
  int* counts = (int*)w;           w += NN * 4;
  int* offs = (int*)w;             w += (NN + 1) * 4;
  int* cursor = (int*)w;           w += NN * 4;
  int* ssrc = (int*)w;             w += ETOT * 4;
  float* stats = (float*)w;        w += 8 * 4;
  float* colsum = (float*)w;       w += 512 * 4;
  float* colsq = (float*)w;        w += 512 * 4;

  const int TPB = 256;
  const int ND_BLK = (int)((ND + TPB - 1) / TPB);
  dim3 mmGrid(36, 8);

  k_xproj<<<ND_BLK, TPB, 0, stream>>>(x, x_proj_w, x_proj_b, h, xg);

  k_init_counts<<<(NN + TPB - 1) / TPB, TPB, 0, stream>>>(counts);
  k_hist<<<(EREAL + TPB - 1) / TPB, TPB, 0, stream>>>(ei, counts);
  k_scan<<<1, 256, 0, stream>>>(counts, offs, cursor);
  k_scatter<<<(ETOT + TPB - 1) / TPB, TPB, 0, stream>>>(ei, cursor, ssrc);

  for (int l = 0; l < NLAYER; l++) {
    const float* Wl = gat_wl + (size_t)l * DD * DD;
    const float* Wr = gat_wr + (size_t)l * DD * DD;
    k_matmul<<<mmGrid, TPB, 0, stream>>>(xg, Wl, gat_bl + l * DD, xl);
    k_matmul<<<mmGrid, TPB, 0, stream>>>(xg, Wr, gat_br + l * DD, xr);
    k_gat_edge<<<NN / 4, TPB, 0, stream>>>(xl, xr, gat_att + l * DD,
                                           gat_bias + l * DD, offs, ssrc, xg);
    if (l < NLAYER - 1) {
      k_zero<<<1, 64, 0, stream>>>(stats, 2);
      k_ln_reduce<<<512, TPB, 0, stream>>>(xg, stats);
      k_ln_norm_relu<<<ND_BLK, TPB, 0, stream>>>(xg, stats, gat_ln_g + l * DD,
                                                 gat_ln_b + l * DD);
    }
  }

  // CloudGraph: g1 = h @ cg_lin1_w (no bias) into xr
  k_matmul<<<mmGrid, TPB, 0, stream>>>(h, cg_lin1_w, nullptr, xr);
  k_cloud<<<NN / 4, TPB, 0, stream>>>(xr, xyz, cei + ECLOUD, cg_lin1_b, cg_xyz_w,
                                      p1, p2);
  k_ln_row<<<NN / 4, TPB, 0, stream>>>(p1, cg_ln_g, cg_ln_b);
  k_zero<<<4, 256, 0, stream>>>(colsum, 1024);  // colsum+colsq contiguous
  k_col_reduce<<<36, 256, 0, stream>>>(p2, colsum, colsq);
  k_bn_apply<<<ND_BLK, TPB, 0, stream>>>(p2, colsum, colsq, cg_bn_g, cg_bn_b);
  k_fuse<<<ND_BLK, TPB, 0, stream>>>(p2, h, xg, p1);

  // final: y = s @ lin_w + lin_b (into xl), then batchnorm -> out
  k_matmul<<<mmGrid, TPB, 0, stream>>>(p2, lin_w, lin_b, xl);
  k_zero<<<4, 256, 0, stream>>>(colsum, 1024);
  k_col_reduce<<<36, 256, 0, stream>>>(xl, colsum, colsq);
  k_bn_out<<<ND_BLK, TPB, 0, stream>>>(xl, colsum, colsq, bn_g, bn_b, (float*)d_out);
}

// Round 3
// 776.371 us; speedup vs baseline: 1.9820x; 1.9820x over previous
//
#include <hip/hip_runtime.h>
#include <hip/hip_bf16.h>

#define NN 4608
#define BG 48
#define NPG 96
#define DD 512
#define XDIM 16
#define EREAL 147456
#define ETOT 152064   // EREAL + NN self loops
#define NLAYER 6
#define NK 262144     // 512*512

typedef __hip_bfloat16 bf16;
typedef short short8 __attribute__((ext_vector_type(8)));
typedef float f32x4 __attribute__((ext_vector_type(4)));

// ---------- weight transpose + bf16 convert: Wt[z][n][k] = W[z][k][n] ----------
__global__ __launch_bounds__(256) void k_wt(const float* __restrict__ wl,
                                            const float* __restrict__ wr,
                                            const float* __restrict__ cg,
                                            const float* __restrict__ lin,
                                            bf16* __restrict__ Wt) {
  __shared__ float tile[32][33];
  int z = blockIdx.z;
  const float* src = (z < 6) ? wl + (size_t)z * NK
                   : (z < 12) ? wr + (size_t)(z - 6) * NK
                   : (z == 12) ? cg : lin;
  bf16* dst = Wt + (size_t)z * NK;
  int c = threadIdx.x & 31;
  int r0 = threadIdx.x >> 5;  // 0..7
  int bx = blockIdx.x * 32, by = blockIdx.y * 32;
#pragma unroll
  for (int i = 0; i < 4; i++) {
    int r = r0 + i * 8;
    tile[r][c] = src[(size_t)(by + r) * 512 + bx + c];  // [k][n]
  }
  __syncthreads();
#pragma unroll
  for (int i = 0; i < 4; i++) {
    int r = r0 + i * 8;  // n within tile
    dst[(size_t)(bx + r) * 512 + by + c] = __float2bfloat16(tile[c][r]);
  }
}

// ---------- x projection: h = x @ Wp + bp ; also bf16 copies ----------
__global__ void k_xproj(const float* __restrict__ x, const float* __restrict__ w,
                        const float* __restrict__ b, float* __restrict__ h,
                        bf16* __restrict__ h_bf, bf16* __restrict__ xg_bf) {
  int i = blockIdx.x * blockDim.x + threadIdx.x;
  if (i >= NN * DD) return;
  int n = i >> 9, d = i & 511;
  float acc = b[d];
#pragma unroll
  for (int k = 0; k < XDIM; k++) acc += x[n * XDIM + k] * w[k * DD + d];
  h[i] = acc;
  bf16 v = __float2bfloat16(acc);
  h_bf[i] = v;
  xg_bf[i] = v;
}

// ---------- edge sort (counting sort by dst) ----------
__global__ void k_init_counts(int* counts) {
  int i = blockIdx.x * blockDim.x + threadIdx.x;
  if (i < NN) counts[i] = 1;  // self loop
}
__global__ void k_hist(const int* __restrict__ ei, int* counts) {
  int e = blockIdx.x * blockDim.x + threadIdx.x;
  if (e < EREAL) atomicAdd(&counts[ei[EREAL + e]], 1);
}
__global__ void k_scan(const int* __restrict__ counts, int* offsets, int* cursor) {
  __shared__ int part[256];
  __shared__ int pre[256];
  int t = threadIdx.x;
  int base = t * 18;  // 4608/256
  int s = 0;
#pragma unroll
  for (int i = 0; i < 18; i++) s += counts[base + i];
  part[t] = s;
  __syncthreads();
  if (t == 0) {
    int r = 0;
    for (int i = 0; i < 256; i++) { pre[i] = r; r += part[i]; }
  }
  __syncthreads();
  int run = pre[t];
#pragma unroll
  for (int i = 0; i < 18; i++) {
    offsets[base + i] = run;
    cursor[base + i] = run;
    run += counts[base + i];
  }
  if (t == 0) offsets[NN] = ETOT;
}
__global__ void k_scatter(const int* __restrict__ ei, int* cursor, int* ssrc) {
  int e = blockIdx.x * blockDim.x + threadIdx.x;
  if (e < EREAL) {
    int s = ei[e], d = ei[EREAL + e];
    int pos = atomicAdd(&cursor[d], 1);
    ssrc[pos] = s;
  } else if (e < ETOT) {
    int n = e - EREAL;
    int pos = atomicAdd(&cursor[n], 1);
    ssrc[pos] = n;
  }
}

// ---------- MFMA GEMM: C[4608,512] = A_bf[4608,512] @ Wt^T + bias ----------
// Wt is [N][K] (pre-transposed). BM=128 BN=64 BK=32, 4 waves, wave=64x32.
// blockIdx.z selects (B0,bias0,C0) or (B1,bias1,C1) for fused pair launches.
__global__ __launch_bounds__(256) void k_gemm(const bf16* __restrict__ A,
                                              const bf16* __restrict__ B0,
                                              const bf16* __restrict__ B1,
                                              const float* __restrict__ bias0,
                                              const float* __restrict__ bias1,
                                              float* __restrict__ C0,
                                              float* __restrict__ C1) {
  __shared__ __align__(16) bf16 As[128 * 40];
  __shared__ __align__(16) bf16 Bs[64 * 40];
  const bf16* B = blockIdx.z ? B1 : B0;
  const float* bias = blockIdx.z ? bias1 : bias0;
  float* C = blockIdx.z ? C1 : C0;
  int tid = threadIdx.x;
  int m0 = blockIdx.x * 128, n0 = blockIdx.y * 64;
  int lane = tid & 63, wid = tid >> 6;
  int mh = (wid >> 1) * 64, nh = (wid & 1) * 32;
  int l15 = lane & 15, quad = lane >> 4;
  f32x4 acc[4][2];
#pragma unroll
  for (int mt = 0; mt < 4; mt++)
#pragma unroll
    for (int nt = 0; nt < 2; nt++) acc[mt][nt] = (f32x4)0.f;

  for (int k0 = 0; k0 < 512; k0 += 32) {
#pragma unroll
    for (int it = 0; it < 2; it++) {
      int c = tid + it * 256;
      int row = c >> 2, kc = (c & 3) * 8;
      *(short8*)&As[row * 40 + kc] =
          *(const short8*)&A[(size_t)(m0 + row) * 512 + k0 + kc];
    }
    {
      int row = tid >> 2, kc = (tid & 3) * 8;
      *(short8*)&Bs[row * 40 + kc] =
          *(const short8*)&B[(size_t)(n0 + row) * 512 + k0 + kc];
    }
    __syncthreads();
    short8 af[4], bfr[2];
#pragma unroll
    for (int mt = 0; mt < 4; mt++)
      af[mt] = *(const short8*)&As[(mh + mt * 16 + l15) * 40 + quad * 8];
#pragma unroll
    for (int nt = 0; nt < 2; nt++)
      bfr[nt] = *(const short8*)&Bs[(nh + nt * 16 + l15) * 40 + quad * 8];
#pragma unroll
    for (int mt = 0; mt < 4; mt++)
#pragma unroll
      for (int nt = 0; nt < 2; nt++)
        acc[mt][nt] = __builtin_amdgcn_mfma_f32_16x16x32_bf16(
            af[mt], bfr[nt], acc[mt][nt], 0, 0, 0);
    __syncthreads();
  }
#pragma unroll
  for (int mt = 0; mt < 4; mt++) {
#pragma unroll
    for (int nt = 0; nt < 2; nt++) {
      int col = n0 + nh + nt * 16 + l15;
      float bv = bias ? bias[col] : 0.f;
#pragma unroll
      for (int r = 0; r < 4; r++) {
        int row = m0 + mh + mt * 16 + quad * 4 + r;
        C[(size_t)row * 512 + col] = acc[mt][nt][r] + bv;
      }
    }
  }
}

// ---------- GAT edge + online softmax + aggregate: one wave per dst node ----------
__global__ __launch_bounds__(256) void k_gat_edge(const float* __restrict__ xl,
                                                  const float* __restrict__ xr,
                                                  const float* __restrict__ att,
                                                  const float* __restrict__ bias,
                                                  const int* __restrict__ offs,
                                                  const int* __restrict__ ssrc,
                                                  float* __restrict__ out) {
  int wave = (blockIdx.x * blockDim.x + threadIdx.x) >> 6;
  int lane = threadIdx.x & 63;
  if (wave >= NN) return;
  int n = wave;
  float xrv[8], attv[8], acc[8];
#pragma unroll
  for (int k = 0; k < 8; k++) {
    int d = k * 64 + lane;
    xrv[k] = xr[(size_t)n * 512 + d];
    attv[k] = att[d];
    acc[k] = 0.f;
  }
  float m = -3.4e38f, lsum = 0.f;
  int e0 = offs[n], e1 = offs[n + 1];
  int e = e0;
  for (; e + 1 < e1; e += 2) {
    int s0 = ssrc[e], s1 = ssrc[e + 1];
    float x0[8], x1[8];
    float sc0 = 0.f, sc1 = 0.f;
#pragma unroll
    for (int k = 0; k < 8; k++) {
      float v0 = xl[(size_t)s0 * 512 + k * 64 + lane];
      float v1 = xl[(size_t)s1 * 512 + k * 64 + lane];
      x0[k] = v0;
      x1[k] = v1;
      float t0 = v0 + xrv[k];
      t0 = (t0 > 0.f) ? t0 : 0.2f * t0;
      sc0 += attv[k] * t0;
      float t1 = v1 + xrv[k];
      t1 = (t1 > 0.f) ? t1 : 0.2f * t1;
      sc1 += attv[k] * t1;
    }
#pragma unroll
    for (int off = 32; off >= 1; off >>= 1) {
      sc0 += __shfl_xor(sc0, off, 64);
      sc1 += __shfl_xor(sc1, off, 64);
    }
    float nm = fmaxf(m, fmaxf(sc0, sc1));
    float sc = __expf(m - nm);
    float p0 = __expf(sc0 - nm);
    float p1 = __expf(sc1 - nm);
    lsum = lsum * sc + p0 + p1;
#pragma unroll
    for (int k = 0; k < 8; k++) acc[k] = acc[k] * sc + p0 * x0[k] + p1 * x1[k];
    m = nm;
  }
  if (e < e1) {
    int s0 = ssrc[e];
    float x0[8];
    float sc0 = 0.f;
#pragma unroll
    for (int k = 0; k < 8; k++) {
      float v0 = xl[(size_t)s0 * 512 + k * 64 + lane];
      x0[k] = v0;
      float t0 = v0 + xrv[k];
      t0 = (t0 > 0.f) ? t0 : 0.2f * t0;
      sc0 += attv[k] * t0;
    }
#pragma unroll
    for (int off = 32; off >= 1; off >>= 1) sc0 += __shfl_xor(sc0, off, 64);
    float nm = fmaxf(m, sc0);
    float sc = __expf(m - nm);
    float p0 = __expf(sc0 - nm);
    lsum = lsum * sc + p0;
#pragma unroll
    for (int k = 0; k < 8; k++) acc[k] = acc[k] * sc + p0 * x0[k];
    m = nm;
  }
  float inv = 1.f / lsum;
#pragma unroll
  for (int k = 0; k < 8; k++) {
    int d = k * 64 + lane;
    out[(size_t)n * 512 + d] = acc[k] * inv + bias[d];
  }
}

// ---------- graph-mode LayerNorm over ALL elements + relu ----------
__global__ void k_zero(float* p, int n) {
  int i = blockIdx.x * blockDim.x + threadIdx.x;
  if (i < n) p[i] = 0.f;
}
__global__ void k_ln_reduce(const float* __restrict__ x, float* stats) {
  float s = 0.f, ss = 0.f;
  for (int i = blockIdx.x * blockDim.x + threadIdx.x; i < NN * DD;
       i += gridDim.x * blockDim.x) {
    float v = x[i];
    s += v;
    ss += v * v;
  }
#pragma unroll
  for (int off = 32; off >= 1; off >>= 1) {
    s += __shfl_xor(s, off, 64);
    ss += __shfl_xor(ss, off, 64);
  }
  __shared__ float sw[2][4];
  int lane = threadIdx.x & 63, w = threadIdx.x >> 6;
  if (lane == 0) { sw[0][w] = s; sw[1][w] = ss; }
  __syncthreads();
  if (threadIdx.x == 0) {
    float a = 0.f, b = 0.f;
    for (int i = 0; i < 4; i++) { a += sw[0][i]; b += sw[1][i]; }
    atomicAdd(&stats[0], a);
    atomicAdd(&stats[1], b);
  }
}
__global__ void k_ln_norm_relu(float* __restrict__ x, const float* __restrict__ stats,
                               const float* __restrict__ g, const float* __restrict__ b,
                               bf16* __restrict__ x_bf) {
  int i = blockIdx.x * blockDim.x + threadIdx.x;
  if (i >= NN * DD) return;
  const float invM = 1.f / (float)(NN * DD);
  float mu = stats[0] * invM;
  float var = stats[1] * invM - mu * mu;
  float sd = sqrtf(fmaxf(var, 0.f));
  float inv = 1.f / (sd + 1e-5f);
  int d = i & 511;
  float v = (x[i] - mu) * inv * g[d] + b[d];
  v = fmaxf(v, 0.f);
  x[i] = v;
  x_bf[i] = __float2bfloat16(v);
}

// ---------- CloudGraph: 2 waves per node, analytic triu edges ----------
__global__ __launch_bounds__(256) void k_cloud(const float* __restrict__ g1,
                                               const float* __restrict__ xyz,
                                               const float* __restrict__ lin1b,
                                               const float* __restrict__ w3,
                                               float* __restrict__ p1,
                                               float* __restrict__ p2) {
  int w = (blockIdx.x * blockDim.x + threadIdx.x) >> 6;
  int lane = threadIdx.x & 63;
  if (w >= NN * 2) return;
  int n = w >> 1;
  int half = (w & 1) * 256;
  int p = n % NPG;
  int cnt = NPG - p;
  float gi[4], bb[4], w30[4], w31[4], w32[4], a1[4], a2[4];
#pragma unroll
  for (int k = 0; k < 4; k++) {
    int d = half + k * 64 + lane;
    gi[k] = g1[(size_t)n * 512 + d];
    bb[k] = lin1b[d];
    w30[k] = w3[d];
    w31[k] = w3[512 + d];
    w32[k] = w3[1024 + d];
    a1[k] = 0.f;
    a2[k] = 0.f;
  }
  float xi0 = xyz[n * 3], xi1 = xyz[n * 3 + 1], xi2 = xyz[n * 3 + 2];
  for (int e = 0; e < cnt; ++e) {
    int j = n + e;  // analytic triu: j = p..95 within graph
    float dx = xi0 - xyz[j * 3];
    float dy = xi1 - xyz[j * 3 + 1];
    float dz = xi2 - xyz[j * 3 + 2];
    float sq = dx * dx + dy * dy + dz * dz;
    float dist = (sq > 0.f) ? sqrtf(sq) : 0.f;
    float wgt = __expf(-dist);
#pragma unroll
    for (int k = 0; k < 4; k++) {
      float t = wgt * (gi[k] - g1[(size_t)j * 512 + half + k * 64 + lane]) + bb[k];
      a1[k] += fmaxf(t, 0.f);
      float t2 = dx * w30[k] + dy * w31[k] + dz * w32[k];
      a2[k] += fmaxf(t2, 0.f);
    }
  }
#pragma unroll
  for (int k = 0; k < 4; k++) {
    int d = half + k * 64 + lane;
    p1[(size_t)n * 512 + d] = a1[k];
    p2[(size_t)n * 512 + d] = a2[k];
  }
}

// ---------- row LayerNorm (cloud ln1), in place ----------
__global__ __launch_bounds__(256) void k_ln_row(float* __restrict__ x,
                                                const float* __restrict__ g,
                                                const float* __restrict__ b) {
  int wave = (blockIdx.x * blockDim.x + threadIdx.x) >> 6;
  int lane = threadIdx.x & 63;
  if (wave >= NN) return;
  int n = wave;
  float v[8];
  float s = 0.f;
#pragma unroll
  for (int k = 0; k < 8; k++) {
    v[k] = x[(size_t)n * 512 + k * 64 + lane];
    s += v[k];
  }
#pragma unroll
  for (int off = 32; off >= 1; off >>= 1) s += __shfl_xor(s, off, 64);
  float mu = s * (1.f / 512.f);
  float ss = 0.f;
#pragma unroll
  for (int k = 0; k < 8; k++) {
    float t = v[k] - mu;
    ss += t * t;
  }
#pragma unroll
  for (int off = 32; off >= 1; off >>= 1) ss += __shfl_xor(ss, off, 64);
  float var = ss * (1.f / 512.f);
  float inv = 1.f / sqrtf(var + 1e-5f);
#pragma unroll
  for (int k = 0; k < 8; k++) {
    int d = k * 64 + lane;
    x[(size_t)n * 512 + d] = (v[k] - mu) * inv * g[d] + b[d];
  }
}

// ---------- column (batchnorm) stats ----------
__global__ void k_col_reduce(const float* __restrict__ x, float* colsum, float* colsq) {
  int r0 = blockIdx.x * 128;
  int c0 = threadIdx.x;
  float s0 = 0.f, q0 = 0.f, s1 = 0.f, q1 = 0.f;
  for (int r = r0; r < r0 + 128; ++r) {
    float v = x[(size_t)r * 512 + c0];
    s0 += v;
    q0 += v * v;
    float w = x[(size_t)r * 512 + c0 + 256];
    s1 += w;
    q1 += w * w;
  }
  atomicAdd(&colsum[c0], s0);
  atomicAdd(&colsq[c0], q0);
  atomicAdd(&colsum[c0 + 256], s1);
  atomicAdd(&colsq[c0 + 256], q1);
}
__global__ void k_bn_apply(float* __restrict__ x, const float* __restrict__ colsum,
                           const float* __restrict__ colsq, const float* __restrict__ g,
                           const float* __restrict__ b) {
  int i = blockIdx.x * blockDim.x + threadIdx.x;
  if (i >= NN * DD) return;
  int d = i & 511;
  float mu = colsum[d] * (1.f / NN);
  float var = colsq[d] * (1.f / NN) - mu * mu;
  float inv = 1.f / sqrtf(fmaxf(var, 0.f) + 1e-5f);
  x[i] = (x[i] - mu) * inv * g[d] + b[d];
}
// s = 2h + xg + p1 + p2 -> bf16 (GEMM A input)
__global__ void k_fuse(const float* __restrict__ p2, const float* __restrict__ h,
                       const float* __restrict__ xg, const float* __restrict__ p1,
                       bf16* __restrict__ s_bf) {
  int i = blockIdx.x * blockDim.x + threadIdx.x;
  if (i >= NN * DD) return;
  s_bf[i] = __float2bfloat16(2.f * h[i] + xg[i] + p1[i] + p2[i]);
}
__global__ void k_bn_out(const float* __restrict__ y, const float* __restrict__ colsum,
                         const float* __restrict__ colsq, const float* __restrict__ g,
                         const float* __restrict__ b, float* __restrict__ out) {
  int i = blockIdx.x * blockDim.x + threadIdx.x;
  if (i >= NN * DD) return;
  int d = i & 511;
  float mu = colsum[d] * (1.f / NN);
  float var = colsq[d] * (1.f / NN) - mu * mu;
  float inv = 1.f / sqrtf(fmaxf(var, 0.f) + 1e-5f);
  out[i] = (y[i] - mu) * inv * g[d] + b[d];
}

extern "C" void kernel_launch(void* const* d_in, const int* in_sizes, int n_in,
                              void* d_out, int out_size, void* d_ws, size_t ws_size,
                              hipStream_t stream) {
  const float* x = (const float*)d_in[0];
  const int* ei = (const int*)d_in[1];
  const float* xyz = (const float*)d_in[3];
  const float* x_proj_w = (const float*)d_in[5];
  const float* x_proj_b = (const float*)d_in[6];
  const float* gat_wl = (const float*)d_in[7];
  const float* gat_bl = (const float*)d_in[8];
  const float* gat_wr = (const float*)d_in[9];
  const float* gat_br = (const float*)d_in[10];
  const float* gat_att = (const float*)d_in[11];
  const float* gat_bias = (const float*)d_in[12];
  const float* gat_ln_g = (const float*)d_in[13];
  const float* gat_ln_b = (const float*)d_in[14];
  const float* cg_xyz_w = (const float*)d_in[15];
  const float* cg_bn_g = (const float*)d_in[16];
  const float* cg_bn_b = (const float*)d_in[17];
  const float* cg_lin1_w = (const float*)d_in[18];
  const float* cg_lin1_b = (const float*)d_in[19];
  const float* cg_ln_g = (const float*)d_in[20];
  const float* cg_ln_b = (const float*)d_in[21];
  const float* lin_w = (const float*)d_in[22];
  const float* lin_b = (const float*)d_in[23];
  const float* bn_g = (const float*)d_in[24];
  const float* bn_b = (const float*)d_in[25];

  const size_t ND = (size_t)NN * DD;
  char* w = (char*)d_ws;
  float* h = (float*)w;       w += ND * 4;
  float* xg = (float*)w;      w += ND * 4;
  float* xl = (float*)w;      w += ND * 4;  // aliases: p1 (after GAT)
  float* xr = (float*)w;      w += ND * 4;  // aliases: g1, final y
  float* p2 = (float*)w;      w += ND * 4;
  bf16* xg_bf = (bf16*)w;     w += ND * 2;
  bf16* h_bf = (bf16*)w;      w += ND * 2;  // aliases: s_bf (after cloud GEMM)
  bf16* Wt = (bf16*)w;        w += (size_t)14 * NK * 2;
  int* counts = (int*)w;      w += NN * 4;
  int* offs = (int*)w;        w += (NN + 4) * 4;
  int* cursor = (int*)w;      w += NN * 4;
  int* ssrc = (int*)w;        w += ETOT * 4;
  float* stats = (float*)w;   w += 8 * 4;
  float* colsum = (float*)w;  w += 512 * 4;
  float* colsq = (float*)w;   w += 512 * 4;
  float* p1 = xl;
  float* g1 = xr;
  float* y = xr;
  bf16* s_bf = h_bf;

  const int TPB = 256;
  const int ND_BLK = (int)((ND + TPB - 1) / TPB);

  k_wt<<<dim3(16, 16, 14), TPB, 0, stream>>>(gat_wl, gat_wr, cg_lin1_w, lin_w, Wt);
  k_xproj<<<ND_BLK, TPB, 0, stream>>>(x, x_proj_w, x_proj_b, h, h_bf, xg_bf);

  k_init_counts<<<(NN + TPB - 1) / TPB, TPB, 0, stream>>>(counts);
  k_hist<<<(EREAL + TPB - 1) / TPB, TPB, 0, stream>>>(ei, counts);
  k_scan<<<1, 256, 0, stream>>>(counts, offs, cursor);
  k_scatter<<<(ETOT + TPB - 1) / TPB, TPB, 0, stream>>>(ei, cursor, ssrc);

  for (int l = 0; l < NLAYER; l++) {
    k_gemm<<<dim3(36, 8, 2), TPB, 0, stream>>>(
        xg_bf, Wt + (size_t)l * NK, Wt + (size_t)(6 + l) * NK,
        gat_bl + l * DD, gat_br + l * DD, xl, xr);
    k_gat_edge<<<NN / 4, TPB, 0, stream>>>(xl, xr, gat_att + l * DD,
                                           gat_bias + l * DD, offs, ssrc, xg);
    if (l < NLAYER - 1) {
      k_zero<<<1, 64, 0, stream>>>(stats, 2);
      k_ln_reduce<<<512, TPB, 0, stream>>>(xg, stats);
      k_ln_norm_relu<<<ND_BLK, TPB, 0, stream>>>(xg, stats, gat_ln_g + l * DD,
                                                 gat_ln_b + l * DD, xg_bf);
    }
  }

  // CloudGraph: g1 = h @ cg_lin1_w (no bias)
  k_gemm<<<dim3(36, 8, 1), TPB, 0, stream>>>(h_bf, Wt + (size_t)12 * NK,
                                             Wt + (size_t)12 * NK, nullptr,
                                             nullptr, g1, g1);
  k_cloud<<<NN / 2, TPB, 0, stream>>>(g1, xyz, cg_lin1_b, cg_xyz_w, p1, p2);
  k_ln_row<<<NN / 4, TPB, 0, stream>>>(p1, cg_ln_g, cg_ln_b);
  k_zero<<<4, 256, 0, stream>>>(colsum, 1024);  // colsum+colsq contiguous
  k_col_reduce<<<36, 256, 0, stream>>>(p2, colsum, colsq);
  k_bn_apply<<<ND_BLK, TPB, 0, stream>>>(p2, colsum, colsq, cg_bn_g, cg_bn_b);
  k_fuse<<<ND_BLK, TPB, 0, stream>>>(p2, h, xg, p1, s_bf);

  // final: y = s @ lin_w + lin_b, then batchnorm -> out
  k_gemm<<<dim3(36, 8, 1), TPB, 0, stream>>>(s_bf, Wt + (size_t)13 * NK,
                                             Wt + (size_t)13 * NK, lin_b, lin_b,
                                             y, y);
  k_zero<<<4, 256, 0, stream>>>(colsum, 1024);
  k_col_reduce<<<36, 256, 0, stream>>>(y, colsum, colsq);
  k_bn_out<<<ND_BLK, TPB, 0, stream>>>(y, colsum, colsq, bn_g, bn_b, (float*)d_out);
}